// Round 2
// baseline (541.354 us; speedup 1.0000x reference)
//
#include <hip/hip_runtime.h>
#include <hip/hip_bf16.h>
#include <stdint.h>

#define NTOK 8192
#define XSTRIDE 259
#define LOG2E 1.4426950408889634f
#define KSPLIT 8
#define SPLEN (NTOK / KSPLIT)   /* 1024 */
#define ITERS (SPLEN / 64)      /* 16 */

typedef __bf16 bf16x8 __attribute__((ext_vector_type(8)));
typedef float f32x4 __attribute__((ext_vector_type(4)));
typedef uint32_t u32x4 __attribute__((ext_vector_type(4)));
typedef unsigned short u16;

union BF8 { u16 u[8]; bf16x8 v; };

__device__ __forceinline__ u16 f2bf(float f) {
  uint32_t u = __float_as_uint(f);
  u += 0x7FFFu + ((u >> 16) & 1u);
  return (u16)(u >> 16);
}
__device__ __forceinline__ float bf2f(u16 h) {
  return __uint_as_float(((uint32_t)h) << 16);
}
__device__ __forceinline__ float exp2_hw(float x) {
  float r; asm("v_exp_f32 %0, %1" : "=v"(r) : "v"(x)); return r;
}
template<int CTRL>
__device__ __forceinline__ float dpp_rot(float x) {
  int i = __float_as_int(x);
  int y = __builtin_amdgcn_update_dpp(i, i, CTRL, 0xF, 0xF, false);
  return __int_as_float(y);
}
__device__ __forceinline__ float rowmax16(float x) {
  x = fmaxf(x, dpp_rot<0x121>(x));
  x = fmaxf(x, dpp_rot<0x122>(x));
  x = fmaxf(x, dpp_rot<0x124>(x));
  x = fmaxf(x, dpp_rot<0x128>(x));
  return x;
}
__device__ __forceinline__ float rowsum16(float x) {
  x += dpp_rot<0x121>(x);
  x += dpp_rot<0x122>(x);
  x += dpp_rot<0x124>(x);
  x += dpp_rot<0x128>(x);
  return x;
}
__device__ __forceinline__ f32x4 mfma16(bf16x8 a, bf16x8 b, f32x4 c) {
  return __builtin_amdgcn_mfma_f32_16x16x32_bf16(a, b, c, 0, 0, 0);
}

// async global->LDS, 16B per lane; LDS dest = uniform base + lane*16
__device__ __forceinline__ void async16(const void* g, void* l) {
  __builtin_amdgcn_global_load_lds(
      (const __attribute__((address_space(1))) uint32_t*)g,
      (__attribute__((address_space(3))) uint32_t*)l, 16, 0, 0);
}

// ---------------------------------------------------------------------------
// Kernel 0: P / |P|^2 precompute.  pq[row] = (px, py, pz, 0.5*|P|^2)
// ---------------------------------------------------------------------------
__global__ void pq_kernel(const float* __restrict__ X, float* __restrict__ pq) {
  int r = blockIdx.x * 256 + threadIdx.x;
  const float* xp = X + (size_t)r * XSTRIDE + 256;
  float x = xp[0], y = xp[1], z = xp[2];
  f32x4 o = { x, y, z, 0.5f * (x * x + y * y + z * z) };
  ((f32x4*)pq)[r] = o;
}

// ---------------------------------------------------------------------------
// Kernel 1: QKV projection (bf16 MFMA).  grid (64 rowblocks, 12 col-chunks).
// ---------------------------------------------------------------------------
__global__ __launch_bounds__(256) void qkv_kernel(
    const float* __restrict__ X,
    const float* __restrict__ WQ, const float* __restrict__ bQ,
    const float* __restrict__ WK, const float* __restrict__ bK,
    const float* __restrict__ WV, const float* __restrict__ bV,
    u16* __restrict__ Qb, u16* __restrict__ Kb, u16* __restrict__ Vt) {
  __shared__ u16 wt[64 * 264];
  const int tid = threadIdx.x;
  const int lane = tid & 63;
  const int wave = tid >> 6;
  const int l15 = lane & 15;
  const int q4 = lane >> 4;
  const int rb = blockIdx.x;
  const int ch = blockIdx.y;
  const int which = ch >> 2;
  const int c0 = (ch & 3) * 64;
  const float* W = (which == 0) ? WQ : ((which == 1) ? WK : WV);
  const float* bias = (which == 0) ? bQ : ((which == 1) ? bK : bV);

  {
    const int j = tid & 63;
    const int k0 = tid >> 6;
#pragma unroll
    for (int i = 0; i < 64; ++i) {
      int k = k0 + i * 4;
      wt[j * 264 + k] = f2bf(W[k * 256 + c0 + j]);
    }
  }
  bf16x8 xa[2][8];
#pragma unroll
  for (int mt = 0; mt < 2; ++mt) {
    const int row = rb * 128 + wave * 32 + mt * 16 + l15;
#pragma unroll
    for (int kc = 0; kc < 8; ++kc) {
      const float* xp = X + (size_t)row * XSTRIDE + kc * 32 + q4 * 8;
      BF8 u;
#pragma unroll
      for (int jj = 0; jj < 8; ++jj) u.u[jj] = f2bf(xp[jj]);
      xa[mt][kc] = u.v;
    }
  }
  __syncthreads();

  f32x4 acc[2][4];
#pragma unroll
  for (int mt = 0; mt < 2; ++mt)
#pragma unroll
    for (int nt = 0; nt < 4; ++nt) acc[mt][nt] = (f32x4){0.f, 0.f, 0.f, 0.f};

#pragma unroll
  for (int kc = 0; kc < 8; ++kc) {
#pragma unroll
    for (int nt = 0; nt < 4; ++nt) {
      bf16x8 wf = *(const bf16x8*)(wt + (nt * 16 + l15) * 264 + kc * 32 + q4 * 8);
#pragma unroll
      for (int mt = 0; mt < 2; ++mt)
        acc[mt][nt] = mfma16(xa[mt][kc], wf, acc[mt][nt]);
    }
  }
  float bc[4];
#pragma unroll
  for (int nt = 0; nt < 4; ++nt) bc[nt] = bias[c0 + nt * 16 + l15];

#pragma unroll
  for (int mt = 0; mt < 2; ++mt)
#pragma unroll
    for (int nt = 0; nt < 4; ++nt)
#pragma unroll
      for (int r = 0; r < 4; ++r) {
        float v = acc[mt][nt][r] + bc[nt];
        int grow = rb * 128 + wave * 32 + mt * 16 + q4 * 4 + r;
        int gc = c0 + nt * 16 + l15;
        if (which == 2)      Vt[(size_t)gc * NTOK + grow] = f2bf(v);
        else if (which == 1) Kb[(size_t)grow * 256 + gc] = f2bf(v);
        else                 Qb[(size_t)grow * 256 + gc] = f2bf(v);
      }
}

// ---------------------------------------------------------------------------
// Kernel 2: flash attention with spatial decay, split-K over keys.
// grid (8 splits, 64 rowblocks) -> linear%8 == split -> same-split blocks on
// one XCD (L2 locality for the 1 MB K/V slice).
// Staging via global_load_lds (no data VGPRs, no spills); XOR chunk swizzle
// (chunk ^= row&7) applied on the global address so unpadded LDS reads stay
// ~conflict-free (2-way only).
// ---------------------------------------------------------------------------
__global__ __launch_bounds__(256, 2) void attn_kernel(
    const u16* __restrict__ Qb, const u16* __restrict__ Kb,
    const u16* __restrict__ Vt, const float* __restrict__ pq,
    u16* __restrict__ Op, float* __restrict__ ml) {
  __shared__ u16 kbuf[64 * 256];   // K tile [64 keys][256], swizzled; P aliased
  __shared__ u16 vbuf[256 * 64];   // V^T tile [256 feat][64 keys], swizzled
  __shared__ float pqs[128][4];

  const int tid = threadIdx.x;
  const int lane = tid & 63;
  const int wave = tid >> 6;
  const int l15 = lane & 15;
  const int q4 = lane >> 4;
  const int sp = blockIdx.x;
  const int rb = blockIdx.y;
  const int q0 = rb * 128;

  if (tid < 128) ((f32x4*)pqs)[tid] = ((const f32x4*)pq)[q0 + tid];

  int zf; asm volatile("s_mov_b32 %0, 0" : "=s"(zf));  // opaque 0

  f32x4 O[2][16];
#pragma unroll
  for (int mt = 0; mt < 2; ++mt)
#pragma unroll
    for (int ft = 0; ft < 16; ++ft) O[mt][ft] = (f32x4){0.f, 0.f, 0.f, 0.f};
  float mrow[8], lrow[8];
#pragma unroll
  for (int i = 0; i < 8; ++i) { mrow[i] = -1e30f; lrow[i] = 0.f; }

  u16* swave = kbuf + wave * (32 * 72);  // per-wave P region aliased on kbuf
  const int wrow = wave * 32;
  const int x3 = l15 & 7;  // row&7 term for swizzled LDS reads

#pragma unroll 1
  for (int it = 0; it < ITERS; ++it) {
    const int key0 = sp * SPLEN + it * 64;

    // ---- async stage K (waves 0,1) and V^T (waves 2,3) ----
    if (wave < 2) {
      const int rb0 = wave * 32;
#pragma unroll
      for (int i = 0; i < 16; ++i) {
        int r = rb0 + i * 2 + (lane >> 5);
        int c = (lane & 31) ^ (r & 7);
        async16(Kb + (size_t)(key0 + r) * 256 + c * 8, kbuf + (rb0 + i * 2) * 256);
      }
    } else {
      const int fb0 = (wave - 2) * 128;
#pragma unroll
      for (int i = 0; i < 16; ++i) {
        int f = fb0 + i * 8 + (lane >> 3);
        int c = (lane & 7) ^ (f & 7);
        async16(Vt + (size_t)f * NTOK + key0 + c * 8, vbuf + (fb0 + i * 8) * 64);
      }
    }
    asm volatile("s_waitcnt vmcnt(0)" ::: "memory");
    __syncthreads();

    // ---- S = Q K^T ----
    f32x4 S[2][4];
#pragma unroll
    for (int mt = 0; mt < 2; ++mt)
#pragma unroll
      for (int nt = 0; nt < 4; ++nt) S[mt][nt] = (f32x4){0.f, 0.f, 0.f, 0.f};

    const u16* qit = Qb + (size_t)(zf * it);
#pragma unroll
    for (int kc = 0; kc < 8; ++kc) {
      bf16x8 qa[2];
#pragma unroll
      for (int mt = 0; mt < 2; ++mt)
        qa[mt] = *(const bf16x8*)(qit + (size_t)(q0 + wrow + mt * 16 + l15) * 256 +
                                  kc * 32 + q4 * 8);
#pragma unroll
      for (int nt = 0; nt < 4; ++nt) {
        bf16x8 kf = *(const bf16x8*)(kbuf + (nt * 16 + l15) * 256 +
                                     (((kc * 4 + q4) ^ x3) * 8));
#pragma unroll
        for (int mt = 0; mt < 2; ++mt)
          S[mt][nt] = mfma16(qa[mt], kf, S[mt][nt]);
      }
    }
    __syncthreads();  // all kbuf reads done before P overwrites it

    // ---- decay + online softmax ----
    f32x4 pk[4];
#pragma unroll
    for (int nt = 0; nt < 4; ++nt)
      pk[nt] = ((const f32x4*)pq)[key0 + nt * 16 + l15];

    float newm[8], rsum[8];
    bool anynew = false;
#pragma unroll
    for (int mt = 0; mt < 2; ++mt) {
#pragma unroll
      for (int r = 0; r < 4; ++r) {
        const int ri = mt * 4 + r;
        f32x4 pr = *(const f32x4*)pqs[wrow + mt * 16 + q4 * 4 + r];
        float xm = -1e30f;
#pragma unroll
        for (int nt = 0; nt < 4; ++nt) {
          float d2h = pr[3] + pk[nt][3] -
                      (pr[0] * pk[nt][0] + pr[1] * pk[nt][1] + pr[2] * pk[nt][2]);
          d2h = fmaxf(d2h, 0.f);
          float dec = exp2_hw(fmaf(d2h, -LOG2E, -4.0f));  // decay/16
          float x = S[mt][nt][r] * dec;
          S[mt][nt][r] = x;
          xm = fmaxf(xm, x);
        }
        xm = rowmax16(xm);
        float nm = fmaxf(mrow[ri], xm);
        newm[ri] = nm;
        anynew |= (nm > mrow[ri]);
        float rs = 0.f;
#pragma unroll
        for (int nt = 0; nt < 4; ++nt) {
          float p = exp2_hw((S[mt][nt][r] - nm) * LOG2E);
          S[mt][nt][r] = p;
          rs += p;
        }
        rsum[ri] = rowsum16(rs);
      }
    }
    if (__any((int)anynew)) {
      float alpha[8];
#pragma unroll
      for (int i = 0; i < 8; ++i) alpha[i] = exp2_hw((mrow[i] - newm[i]) * LOG2E);
#pragma unroll
      for (int mt = 0; mt < 2; ++mt)
#pragma unroll
        for (int ft = 0; ft < 16; ++ft)
#pragma unroll
          for (int r = 0; r < 4; ++r) O[mt][ft][r] *= alpha[mt * 4 + r];
#pragma unroll
      for (int i = 0; i < 8; ++i) lrow[i] = lrow[i] * alpha[i] + rsum[i];
    } else {
#pragma unroll
      for (int i = 0; i < 8; ++i) lrow[i] += rsum[i];
    }
#pragma unroll
    for (int i = 0; i < 8; ++i) mrow[i] = newm[i];

    // ---- P tile (bf16) into per-wave LDS region (aliased on kbuf) ----
#pragma unroll
    for (int mt = 0; mt < 2; ++mt)
#pragma unroll
      for (int nt = 0; nt < 4; ++nt)
#pragma unroll
        for (int r = 0; r < 4; ++r)
          swave[(mt * 16 + q4 * 4 + r) * 72 + nt * 16 + l15] = f2bf(S[mt][nt][r]);

    // ---- O += P V ----
#pragma unroll
    for (int kc2 = 0; kc2 < 2; ++kc2) {
      bf16x8 pa[2];
#pragma unroll
      for (int mt = 0; mt < 2; ++mt)
        pa[mt] = *(const bf16x8*)(swave + (mt * 16 + l15) * 72 + kc2 * 32 + q4 * 8);
#pragma unroll
      for (int ft = 0; ft < 16; ++ft) {
        bf16x8 vf = *(const bf16x8*)(vbuf + (ft * 16 + l15) * 64 +
                                     (((kc2 * 4 + q4) ^ x3) * 8));
#pragma unroll
        for (int mt = 0; mt < 2; ++mt)
          O[mt][ft] = mfma16(pa[mt], vf, O[mt][ft]);
      }
    }
    __syncthreads();  // P/V reads done before next iteration's staging
  }

  // ---- write partial O, (m, l) ----
#pragma unroll
  for (int mt = 0; mt < 2; ++mt)
#pragma unroll
    for (int ft = 0; ft < 16; ++ft)
#pragma unroll
      for (int r = 0; r < 4; ++r) {
        int row = q0 + wrow + mt * 16 + q4 * 4 + r;
        Op[((size_t)sp * NTOK + row) * 256 + ft * 16 + l15] = f2bf(O[mt][ft][r]);
      }
  if (l15 == 0) {
#pragma unroll
    for (int mt = 0; mt < 2; ++mt)
#pragma unroll
      for (int r = 0; r < 4; ++r) {
        int row = q0 + wrow + mt * 16 + q4 * 4 + r;
        ((float2*)ml)[sp * NTOK + row] = make_float2(mrow[mt * 4 + r], lrow[mt * 4 + r]);
      }
  }
}

// ---------------------------------------------------------------------------
// Kernel 3: combine splits, normalize with (1 + sum e), add residual Xf.
// ---------------------------------------------------------------------------
__global__ __launch_bounds__(256) void combine_kernel(
    const float* __restrict__ X, const u16* __restrict__ Op,
    const float* __restrict__ ml, float* __restrict__ out) {
  const int row = blockIdx.x;
  const int f = threadIdx.x;
  float mm[KSPLIT], ll[KSPLIT];
  float M = -1e30f;
#pragma unroll
  for (int s = 0; s < KSPLIT; ++s) {
    float2 v = ((const float2*)ml)[s * NTOK + row];
    mm[s] = v.x; ll[s] = v.y;
    M = fmaxf(M, v.x);
  }
  float den = 1.f, num = 0.f;
#pragma unroll
  for (int s = 0; s < KSPLIT; ++s) {
    float w = exp2_hw((mm[s] - M) * LOG2E);
    den += ll[s] * w;
    num += bf2f(Op[((size_t)s * NTOK + row) * 256 + f]) * w;
  }
  out[(size_t)row * 256 + f] = num / den + X[(size_t)row * XSTRIDE + f];
}

// ---------------------------------------------------------------------------
extern "C" void kernel_launch(void* const* d_in, const int* in_sizes, int n_in,
                              void* d_out, int out_size, void* d_ws, size_t ws_size,
                              hipStream_t stream) {
  (void)in_sizes; (void)n_in; (void)out_size; (void)ws_size;
  const float* X  = (const float*)d_in[0];
  const float* WQ = (const float*)d_in[1];
  const float* bQ = (const float*)d_in[2];
  const float* WK = (const float*)d_in[3];
  const float* bK = (const float*)d_in[4];
  const float* WV = (const float*)d_in[5];
  const float* bV = (const float*)d_in[6];
  float* out = (float*)d_out;
  char* ws = (char*)d_ws;

  u16*   Qb = (u16*)(ws);
  u16*   Kb = (u16*)(ws + (size_t)4 * 1024 * 1024);
  u16*   Vt = (u16*)(ws + (size_t)8 * 1024 * 1024);
  float* pq = (float*)(ws + (size_t)12 * 1024 * 1024);
  u16*   Op = (u16*)(ws + (size_t)12 * 1024 * 1024 + 131072);
  float* ml = (float*)(ws + (size_t)12 * 1024 * 1024 + 131072 +
                       (size_t)KSPLIT * NTOK * 256 * 2);

  pq_kernel<<<dim3(NTOK / 256), dim3(256), 0, stream>>>(X, pq);
  qkv_kernel<<<dim3(64, 12), dim3(256), 0, stream>>>(X, WQ, bQ, WK, bK, WV, bV,
                                                     Qb, Kb, Vt);
  attn_kernel<<<dim3(KSPLIT, 64), dim3(256), 0, stream>>>(Qb, Kb, Vt, pq, Op, ml);
  combine_kernel<<<dim3(NTOK), dim3(256), 0, stream>>>(X, Op, ml, out);
}

// Round 4
// 281.311 us; speedup vs baseline: 1.9244x; 1.9244x over previous
//
#include <hip/hip_runtime.h>
#include <hip/hip_bf16.h>
#include <stdint.h>

#define NTOK 8192
#define XSTRIDE 259
#define LOG2E 1.4426950408889634f
#define KSPLIT 8
#define SPLEN (NTOK / KSPLIT)   /* 1024 */
#define ITERS (SPLEN / 64)      /* 16 */

typedef __bf16 bf16x8 __attribute__((ext_vector_type(8)));
typedef float f32x4 __attribute__((ext_vector_type(4)));
typedef unsigned short u16;

union BF8 { u16 u[8]; bf16x8 v; };

__device__ __forceinline__ u16 f2bf(float f) {
  uint32_t u = __float_as_uint(f);
  u += 0x7FFFu + ((u >> 16) & 1u);
  return (u16)(u >> 16);
}
__device__ __forceinline__ float bf2f(u16 h) {
  return __uint_as_float(((uint32_t)h) << 16);
}
__device__ __forceinline__ float exp2_hw(float x) {
  float r; asm("v_exp_f32 %0, %1" : "=v"(r) : "v"(x)); return r;
}
template<int CTRL>
__device__ __forceinline__ float dpp_rot(float x) {
  int i = __float_as_int(x);
  int y = __builtin_amdgcn_update_dpp(i, i, CTRL, 0xF, 0xF, false);
  return __int_as_float(y);
}
// sum across the 16-lane DPP row (lanes sharing q4) — epilogue only
__device__ __forceinline__ float rowsum16(float x) {
  x += dpp_rot<0x121>(x);
  x += dpp_rot<0x122>(x);
  x += dpp_rot<0x124>(x);
  x += dpp_rot<0x128>(x);
  return x;
}
__device__ __forceinline__ f32x4 mfma16(bf16x8 a, bf16x8 b, f32x4 c) {
  return __builtin_amdgcn_mfma_f32_16x16x32_bf16(a, b, c, 0, 0, 0);
}

// async global->LDS, 16B per lane; LDS dest = uniform base + lane*16
__device__ __forceinline__ void async16(const void* g, void* l) {
  __builtin_amdgcn_global_load_lds(
      (const __attribute__((address_space(1))) uint32_t*)g,
      (__attribute__((address_space(3))) uint32_t*)l, 16, 0, 0);
}

// ---------------------------------------------------------------------------
// Kernel 0: P / |P|^2 precompute.  pq[row] = (px, py, pz, 0.5*|P|^2)
// ---------------------------------------------------------------------------
__global__ void pq_kernel(const float* __restrict__ X, float* __restrict__ pq) {
  int r = blockIdx.x * 256 + threadIdx.x;
  const float* xp = X + (size_t)r * XSTRIDE + 256;
  float x = xp[0], y = xp[1], z = xp[2];
  f32x4 o = { x, y, z, 0.5f * (x * x + y * y + z * z) };
  ((f32x4*)pq)[r] = o;
}

// ---------------------------------------------------------------------------
// Kernel 1: QKV projection (bf16 MFMA).  grid (64 rowblocks, 12 col-chunks).
// ---------------------------------------------------------------------------
__global__ __launch_bounds__(256) void qkv_kernel(
    const float* __restrict__ X,
    const float* __restrict__ WQ, const float* __restrict__ bQ,
    const float* __restrict__ WK, const float* __restrict__ bK,
    const float* __restrict__ WV, const float* __restrict__ bV,
    u16* __restrict__ Qb, u16* __restrict__ Kb, u16* __restrict__ Vt) {
  __shared__ u16 wt[64 * 264];
  const int tid = threadIdx.x;
  const int lane = tid & 63;
  const int wave = tid >> 6;
  const int l15 = lane & 15;
  const int q4 = lane >> 4;
  const int rb = blockIdx.x;
  const int ch = blockIdx.y;
  const int which = ch >> 2;
  const int c0 = (ch & 3) * 64;
  const float* W = (which == 0) ? WQ : ((which == 1) ? WK : WV);
  const float* bias = (which == 0) ? bQ : ((which == 1) ? bK : bV);

  {
    const int j = tid & 63;
    const int k0 = tid >> 6;
#pragma unroll
    for (int i = 0; i < 64; ++i) {
      int k = k0 + i * 4;
      wt[j * 264 + k] = f2bf(W[k * 256 + c0 + j]);
    }
  }
  bf16x8 xa[2][8];
#pragma unroll
  for (int mt = 0; mt < 2; ++mt) {
    const int row = rb * 128 + wave * 32 + mt * 16 + l15;
#pragma unroll
    for (int kc = 0; kc < 8; ++kc) {
      const float* xp = X + (size_t)row * XSTRIDE + kc * 32 + q4 * 8;
      BF8 u;
#pragma unroll
      for (int jj = 0; jj < 8; ++jj) u.u[jj] = f2bf(xp[jj]);
      xa[mt][kc] = u.v;
    }
  }
  __syncthreads();

  f32x4 acc[2][4];
#pragma unroll
  for (int mt = 0; mt < 2; ++mt)
#pragma unroll
    for (int nt = 0; nt < 4; ++nt) acc[mt][nt] = (f32x4){0.f, 0.f, 0.f, 0.f};

#pragma unroll
  for (int kc = 0; kc < 8; ++kc) {
#pragma unroll
    for (int nt = 0; nt < 4; ++nt) {
      bf16x8 wf = *(const bf16x8*)(wt + (nt * 16 + l15) * 264 + kc * 32 + q4 * 8);
#pragma unroll
      for (int mt = 0; mt < 2; ++mt)
        acc[mt][nt] = mfma16(xa[mt][kc], wf, acc[mt][nt]);
    }
  }
  float bc[4];
#pragma unroll
  for (int nt = 0; nt < 4; ++nt) bc[nt] = bias[c0 + nt * 16 + l15];

#pragma unroll
  for (int mt = 0; mt < 2; ++mt)
#pragma unroll
    for (int nt = 0; nt < 4; ++nt)
#pragma unroll
      for (int r = 0; r < 4; ++r) {
        float v = acc[mt][nt][r] + bc[nt];
        int grow = rb * 128 + wave * 32 + mt * 16 + q4 * 4 + r;
        int gc = c0 + nt * 16 + l15;
        if (which == 2)      Vt[(size_t)gc * NTOK + grow] = f2bf(v);
        else if (which == 1) Kb[(size_t)grow * 256 + gc] = f2bf(v);
        else                 Qb[(size_t)grow * 256 + gc] = f2bf(v);
      }
}

// ---------------------------------------------------------------------------
// Kernel 2: flash attention with spatial decay, split-K over keys.
// Fixed-reference exp (x = S*decay/16 provably in [-4,4], no overflow);
// row-sums deferred to epilogue. P round-trips through LDS aliased on kbuf;
// EVERY region transition is now barrier-separated:
//   stage -> b -> QK reads kbuf -> b -> P writes (kbuf alias) -> b ->
//   PV reads -> b -> next stage.
// The P-write -> PV-read edge previously had no barrier; write(u16*) vs
// read(bf16x8*) are no-alias under TBAA so the compiler may hoist the reads
// above the writes — the R3 post-timing divergence. Barrier pins it.
// ---------------------------------------------------------------------------
__global__ __launch_bounds__(256, 2) void attn_kernel(
    const u16* __restrict__ Qb, const u16* __restrict__ Kb,
    const u16* __restrict__ Vt, const float* __restrict__ pq,
    u16* __restrict__ Op, float* __restrict__ ml) {
  __shared__ u16 kbuf[64 * 256];   // K tile [64 keys][256], swizzled; P aliased
  __shared__ u16 vbuf[256 * 64];   // V^T tile [256 feat][64 keys], swizzled
  __shared__ float pqs[128][4];

  const int tid = threadIdx.x;
  const int lane = tid & 63;
  const int wave = tid >> 6;
  const int l15 = lane & 15;
  const int q4 = lane >> 4;
  const int rb = blockIdx.x;
  const int sp = blockIdx.y;
  const int q0 = rb * 128;

  if (tid < 128) ((f32x4*)pqs)[tid] = ((const f32x4*)pq)[q0 + tid];

  int zf; asm volatile("s_mov_b32 %0, 0" : "=s"(zf));  // opaque 0

  f32x4 O[2][16];
#pragma unroll
  for (int mt = 0; mt < 2; ++mt)
#pragma unroll
    for (int ft = 0; ft < 16; ++ft) O[mt][ft] = (f32x4){0.f, 0.f, 0.f, 0.f};
  float lrow[8];
#pragma unroll
  for (int i = 0; i < 8; ++i) lrow[i] = 0.f;

  u16* swave = kbuf + wave * (32 * 72);  // per-wave P region aliased on kbuf
  const int wrow = wave * 32;
  const int x3 = l15 & 7;

#pragma unroll 1
  for (int it = 0; it < ITERS; ++it) {
    const int key0 = sp * SPLEN + it * 64;

    // ---- async stage K (waves 0,1) and V^T (waves 2,3) ----
    if (wave < 2) {
      const int rb0 = wave * 32;
#pragma unroll
      for (int i = 0; i < 16; ++i) {
        int r = rb0 + i * 2 + (lane >> 5);
        int c = (lane & 31) ^ (r & 7);
        async16(Kb + (size_t)(key0 + r) * 256 + c * 8, kbuf + (rb0 + i * 2) * 256);
      }
    } else {
      const int fb0 = (wave - 2) * 128;
#pragma unroll
      for (int i = 0; i < 16; ++i) {
        int f = fb0 + i * 8 + (lane >> 3);
        int c = (lane & 7) ^ (f & 7);
        async16(Vt + (size_t)f * NTOK + key0 + c * 8, vbuf + (fb0 + i * 8) * 64);
      }
    }
    asm volatile("s_waitcnt vmcnt(0)" ::: "memory");
    __syncthreads();

    // ---- S = Q K^T ----
    f32x4 S[2][4];
#pragma unroll
    for (int mt = 0; mt < 2; ++mt)
#pragma unroll
      for (int nt = 0; nt < 4; ++nt) S[mt][nt] = (f32x4){0.f, 0.f, 0.f, 0.f};

    const u16* qit = Qb + (size_t)(zf * it);
#pragma unroll
    for (int kc = 0; kc < 8; ++kc) {
      bf16x8 qa[2];
#pragma unroll
      for (int mt = 0; mt < 2; ++mt)
        qa[mt] = *(const bf16x8*)(qit + (size_t)(q0 + wrow + mt * 16 + l15) * 256 +
                                  kc * 32 + q4 * 8);
#pragma unroll
      for (int nt = 0; nt < 4; ++nt) {
        bf16x8 kf = *(const bf16x8*)(kbuf + (nt * 16 + l15) * 256 +
                                     (((kc * 4 + q4) ^ x3) * 8));
#pragma unroll
        for (int mt = 0; mt < 2; ++mt)
          S[mt][nt] = mfma16(qa[mt], kf, S[mt][nt]);
      }
    }
    __syncthreads();  // all kbuf reads done before P overwrites it

    // ---- decay + exp (fixed reference; no max, no rescale) ----
    f32x4 pk[4];
#pragma unroll
    for (int nt = 0; nt < 4; ++nt)
      pk[nt] = ((const f32x4*)pq)[key0 + nt * 16 + l15];

#pragma unroll
    for (int mt = 0; mt < 2; ++mt) {
#pragma unroll
      for (int r = 0; r < 4; ++r) {
        const int ri = mt * 4 + r;
        f32x4 pr = *(const f32x4*)pqs[wrow + mt * 16 + q4 * 4 + r];
        float lacc = 0.f;
#pragma unroll
        for (int nt = 0; nt < 4; ++nt) {
          float d2h = pr[3] + pk[nt][3] -
                      (pr[0] * pk[nt][0] + pr[1] * pk[nt][1] + pr[2] * pk[nt][2]);
          d2h = fmaxf(d2h, 0.f);
          float dec = exp2_hw(fmaf(d2h, -LOG2E, -4.0f));  // decay/16
          float p = exp2_hw(S[mt][nt][r] * dec * LOG2E);
          S[mt][nt][r] = p;
          lacc += p;
        }
        lrow[ri] += lacc;
      }
    }

    // ---- P tile (bf16) into per-wave LDS region (aliased on kbuf) ----
    asm volatile("" ::: "memory");
#pragma unroll
    for (int mt = 0; mt < 2; ++mt)
#pragma unroll
      for (int nt = 0; nt < 4; ++nt)
#pragma unroll
        for (int r = 0; r < 4; ++r)
          swave[(mt * 16 + q4 * 4 + r) * 72 + nt * 16 + l15] = f2bf(S[mt][nt][r]);

    __syncthreads();  // P writes ordered before PV reads (TBAA: u16* store vs
                      // bf16x8* load don't alias — barrier pins the schedule)

    // ---- O += P V ----
#pragma unroll
    for (int kc2 = 0; kc2 < 2; ++kc2) {
      bf16x8 pa[2];
#pragma unroll
      for (int mt = 0; mt < 2; ++mt)
        pa[mt] = *(const bf16x8*)(swave + (mt * 16 + l15) * 72 + kc2 * 32 + q4 * 8);
#pragma unroll
      for (int ft = 0; ft < 16; ++ft) {
        bf16x8 vf = *(const bf16x8*)(vbuf + (ft * 16 + l15) * 64 +
                                     (((kc2 * 4 + q4) ^ x3) * 8));
#pragma unroll
        for (int mt = 0; mt < 2; ++mt)
          O[mt][ft] = mfma16(pa[mt], vf, O[mt][ft]);
      }
    }
    asm volatile("" ::: "memory");
    __syncthreads();  // P/V reads done before next iteration's staging
  }

  // ---- epilogue: cross-lane row sums, write partial O and l ----
#pragma unroll
  for (int i = 0; i < 8; ++i) lrow[i] = rowsum16(lrow[i]);

#pragma unroll
  for (int mt = 0; mt < 2; ++mt)
#pragma unroll
    for (int ft = 0; ft < 16; ++ft)
#pragma unroll
      for (int r = 0; r < 4; ++r) {
        int row = q0 + wrow + mt * 16 + q4 * 4 + r;
        Op[((size_t)sp * NTOK + row) * 256 + ft * 16 + l15] = f2bf(O[mt][ft][r]);
      }
  if (l15 == 0) {
#pragma unroll
    for (int mt = 0; mt < 2; ++mt)
#pragma unroll
      for (int r = 0; r < 4; ++r) {
        int row = q0 + wrow + mt * 16 + q4 * 4 + r;
        ml[sp * NTOK + row] = lrow[mt * 4 + r];
      }
  }
}

// ---------------------------------------------------------------------------
// Kernel 3: combine splits: H = (sum O_s) / (1 + sum l_s) + residual.
// ---------------------------------------------------------------------------
__global__ __launch_bounds__(256) void combine_kernel(
    const float* __restrict__ X, const u16* __restrict__ Op,
    const float* __restrict__ ml, float* __restrict__ out) {
  const int row = blockIdx.x;
  const int f = threadIdx.x;
  float den = 1.f, num = 0.f;
#pragma unroll
  for (int s = 0; s < KSPLIT; ++s) {
    den += ml[s * NTOK + row];
    num += bf2f(Op[((size_t)s * NTOK + row) * 256 + f]);
  }
  out[(size_t)row * 256 + f] = num / den + X[(size_t)row * XSTRIDE + f];
}

// ---------------------------------------------------------------------------
extern "C" void kernel_launch(void* const* d_in, const int* in_sizes, int n_in,
                              void* d_out, int out_size, void* d_ws, size_t ws_size,
                              hipStream_t stream) {
  (void)in_sizes; (void)n_in; (void)out_size; (void)ws_size;
  const float* X  = (const float*)d_in[0];
  const float* WQ = (const float*)d_in[1];
  const float* bQ = (const float*)d_in[2];
  const float* WK = (const float*)d_in[3];
  const float* bK = (const float*)d_in[4];
  const float* WV = (const float*)d_in[5];
  const float* bV = (const float*)d_in[6];
  float* out = (float*)d_out;
  char* ws = (char*)d_ws;

  u16*   Qb = (u16*)(ws);
  u16*   Kb = (u16*)(ws + (size_t)4 * 1024 * 1024);
  u16*   Vt = (u16*)(ws + (size_t)8 * 1024 * 1024);
  float* pq = (float*)(ws + (size_t)12 * 1024 * 1024);
  u16*   Op = (u16*)(ws + (size_t)12 * 1024 * 1024 + 131072);
  float* ml = (float*)(ws + (size_t)12 * 1024 * 1024 + 131072 +
                       (size_t)KSPLIT * NTOK * 256 * 2);

  pq_kernel<<<dim3(NTOK / 256), dim3(256), 0, stream>>>(X, pq);
  qkv_kernel<<<dim3(64, 12), dim3(256), 0, stream>>>(X, WQ, bQ, WK, bK, WV, bV,
                                                     Qb, Kb, Vt);
  attn_kernel<<<dim3(64, KSPLIT), dim3(256), 0, stream>>>(Qb, Kb, Vt, pq, Op, ml);
  combine_kernel<<<dim3(NTOK), dim3(256), 0, stream>>>(X, Op, ml, out);
}

// Round 5
// 252.957 us; speedup vs baseline: 2.1401x; 1.1121x over previous
//
#include <hip/hip_runtime.h>
#include <hip/hip_bf16.h>
#include <stdint.h>

#define NTOK 8192
#define XSTRIDE 259
#define LOG2E 1.4426950408889634f
#define DECC (-3.4712336270551023f)   /* -4 + log2(log2 e): folds LOG2E into decay */
#define KSPLIT 4
#define SPLEN (NTOK / KSPLIT)   /* 2048 */
#define BN 32
#define ITERS (SPLEN / BN)      /* 64 */

typedef __bf16 bf16x8 __attribute__((ext_vector_type(8)));
typedef float f32x4 __attribute__((ext_vector_type(4)));
typedef unsigned short u16;

union BF8 { u16 u[8]; bf16x8 v; };

__device__ __forceinline__ u16 f2bf(float f) {
  uint32_t u = __float_as_uint(f);
  u += 0x7FFFu + ((u >> 16) & 1u);
  return (u16)(u >> 16);
}
__device__ __forceinline__ float bf2f(u16 h) {
  return __uint_as_float(((uint32_t)h) << 16);
}
__device__ __forceinline__ uint32_t pk_bf(float a, float b) {
  union { __hip_bfloat162 h; uint32_t u; } cv;
  cv.h = __float22bfloat162_rn(make_float2(a, b));
  return cv.u;
}
__device__ __forceinline__ float exp2_hw(float x) {
  float r; asm("v_exp_f32 %0, %1" : "=v"(r) : "v"(x)); return r;
}
template<int CTRL>
__device__ __forceinline__ float dpp_rot(float x) {
  int i = __float_as_int(x);
  int y = __builtin_amdgcn_update_dpp(i, i, CTRL, 0xF, 0xF, false);
  return __int_as_float(y);
}
__device__ __forceinline__ float rowsum16(float x) {
  x += dpp_rot<0x121>(x);
  x += dpp_rot<0x122>(x);
  x += dpp_rot<0x124>(x);
  x += dpp_rot<0x128>(x);
  return x;
}
__device__ __forceinline__ f32x4 mfma16(bf16x8 a, bf16x8 b, f32x4 c) {
  return __builtin_amdgcn_mfma_f32_16x16x32_bf16(a, b, c, 0, 0, 0);
}

// async global->LDS, 16B per lane; LDS dest = uniform base + lane*16
__device__ __forceinline__ void async16(const void* g, void* l) {
  __builtin_amdgcn_global_load_lds(
      (const __attribute__((address_space(1))) uint32_t*)g,
      (__attribute__((address_space(3))) uint32_t*)l, 16, 0, 0);
}

// ---------------------------------------------------------------------------
// Kernel 0: P / |P|^2 precompute.  pq[row] = (px, py, pz, 0.5*|P|^2)
// ---------------------------------------------------------------------------
__global__ void pq_kernel(const float* __restrict__ X, float* __restrict__ pq) {
  int r = blockIdx.x * 256 + threadIdx.x;
  const float* xp = X + (size_t)r * XSTRIDE + 256;
  float x = xp[0], y = xp[1], z = xp[2];
  f32x4 o = { x, y, z, 0.5f * (x * x + y * y + z * z) };
  ((f32x4*)pq)[r] = o;
}

// ---------------------------------------------------------------------------
// Kernel 1: QKV projection (bf16 MFMA).  grid (64 rowblocks, 12 col-chunks).
// ---------------------------------------------------------------------------
__global__ __launch_bounds__(256) void qkv_kernel(
    const float* __restrict__ X,
    const float* __restrict__ WQ, const float* __restrict__ bQ,
    const float* __restrict__ WK, const float* __restrict__ bK,
    const float* __restrict__ WV, const float* __restrict__ bV,
    u16* __restrict__ Qb, u16* __restrict__ Kb, u16* __restrict__ Vt) {
  __shared__ u16 wt[64 * 264];
  const int tid = threadIdx.x;
  const int lane = tid & 63;
  const int wave = tid >> 6;
  const int l15 = lane & 15;
  const int q4 = lane >> 4;
  const int rb = blockIdx.x;
  const int ch = blockIdx.y;
  const int which = ch >> 2;
  const int c0 = (ch & 3) * 64;
  const float* W = (which == 0) ? WQ : ((which == 1) ? WK : WV);
  const float* bias = (which == 0) ? bQ : ((which == 1) ? bK : bV);

  {
    const int j = tid & 63;
    const int k0 = tid >> 6;
#pragma unroll
    for (int i = 0; i < 64; ++i) {
      int k = k0 + i * 4;
      wt[j * 264 + k] = f2bf(W[k * 256 + c0 + j]);
    }
  }
  bf16x8 xa[2][8];
#pragma unroll
  for (int mt = 0; mt < 2; ++mt) {
    const int row = rb * 128 + wave * 32 + mt * 16 + l15;
#pragma unroll
    for (int kc = 0; kc < 8; ++kc) {
      const float* xp = X + (size_t)row * XSTRIDE + kc * 32 + q4 * 8;
      BF8 u;
#pragma unroll
      for (int jj = 0; jj < 8; ++jj) u.u[jj] = f2bf(xp[jj]);
      xa[mt][kc] = u.v;
    }
  }
  __syncthreads();

  f32x4 acc[2][4];
#pragma unroll
  for (int mt = 0; mt < 2; ++mt)
#pragma unroll
    for (int nt = 0; nt < 4; ++nt) acc[mt][nt] = (f32x4){0.f, 0.f, 0.f, 0.f};

#pragma unroll
  for (int kc = 0; kc < 8; ++kc) {
#pragma unroll
    for (int nt = 0; nt < 4; ++nt) {
      bf16x8 wf = *(const bf16x8*)(wt + (nt * 16 + l15) * 264 + kc * 32 + q4 * 8);
#pragma unroll
      for (int mt = 0; mt < 2; ++mt)
        acc[mt][nt] = mfma16(xa[mt][kc], wf, acc[mt][nt]);
    }
  }
  float bc[4];
#pragma unroll
  for (int nt = 0; nt < 4; ++nt) bc[nt] = bias[c0 + nt * 16 + l15];

#pragma unroll
  for (int mt = 0; mt < 2; ++mt)
#pragma unroll
    for (int nt = 0; nt < 4; ++nt)
#pragma unroll
      for (int r = 0; r < 4; ++r) {
        float v = acc[mt][nt][r] + bc[nt];
        int grow = rb * 128 + wave * 32 + mt * 16 + q4 * 4 + r;
        int gc = c0 + nt * 16 + l15;
        if (which == 2)      Vt[(size_t)gc * NTOK + grow] = f2bf(v);
        else if (which == 1) Kb[(size_t)grow * 256 + gc] = f2bf(v);
        else                 Qb[(size_t)grow * 256 + gc] = f2bf(v);
      }
}

// ---------------------------------------------------------------------------
// Kernel 2: flash attention, prefetch-pipelined.
//   BN=32 keys/iter, double-buffered K/V staged via global_load_lds,
//   prefetch issued one full iteration ahead -> vmcnt(0) at iter top is free.
//   ONE barrier per iteration. Q persistent in registers (loaded pre-loop;
//   no in-loop global loads, so nothing drains the prefetch queue).
//   P round-trip via dedicated per-wave pbuf (stride 40 u16 = 80 B, 16B
//   aligned): same-wave write->read ordered by lgkmcnt(0) + compiler fence;
//   cross-iteration reuse ordered by the per-iter barrier.
//   __launch_bounds__(256,1): 1 block/CU, 512-reg budget -> no spill.
// ---------------------------------------------------------------------------
__global__ __launch_bounds__(256, 1) void attn_kernel(
    const u16* __restrict__ Qb, const u16* __restrict__ Kb,
    const u16* __restrict__ Vt, const float* __restrict__ pq,
    u16* __restrict__ Op, float* __restrict__ ml) {
  __shared__ u16 kbuf[2][BN * 256];     // 16 KB x2, rows 512 B, xor-swizzled
  __shared__ u16 vbuf[2][256 * BN];     // 16 KB x2, rows 64 B, xor-swizzled
  __shared__ u16 pbuf[4][32 * 40];      // per-wave P, stride 40 u16 (80 B)
  __shared__ float pqs[128][4];

  const int tid = threadIdx.x;
  const int lane = tid & 63;
  const int wave = tid >> 6;
  const int l15 = lane & 15;
  const int q4 = lane >> 4;
  const int rb = blockIdx.x;
  const int sp = blockIdx.y;
  const int q0 = rb * 128;
  const int wrow = wave * 32;

  if (tid < 128) ((f32x4*)pqs)[tid] = ((const f32x4*)pq)[q0 + tid];

#define STAGE_KV(KEY0, B)                                                     \
  do {                                                                        \
    if (wave < 2) {                                                           \
      const int rb0 = wave * 16;                                              \
      _Pragma("unroll")                                                       \
      for (int i = 0; i < 8; ++i) {                                           \
        int r = rb0 + i * 2 + (lane >> 5);                                    \
        int c = (lane & 31) ^ (r & 7);                                        \
        async16(Kb + (size_t)((KEY0) + r) * 256 + c * 8,                      \
                &kbuf[B][(rb0 + i * 2) * 256]);                               \
      }                                                                       \
    } else {                                                                  \
      const int fb0 = (wave - 2) * 128;                                       \
      _Pragma("unroll")                                                       \
      for (int i = 0; i < 8; ++i) {                                           \
        int f = fb0 + i * 16 + (lane >> 2);                                   \
        int c = (lane & 3) ^ (f & 3);                                         \
        async16(Vt + (size_t)f * NTOK + (KEY0) + c * 8,                       \
                &vbuf[B][(fb0 + i * 16) * 32]);                               \
      }                                                                       \
    }                                                                         \
  } while (0)

  // ---- Q fragments: loaded once, live in registers for the whole kernel ----
  bf16x8 qa[2][8];
#pragma unroll
  for (int mt = 0; mt < 2; ++mt)
#pragma unroll
    for (int kc = 0; kc < 8; ++kc)
      qa[mt][kc] = *(const bf16x8*)(Qb + (size_t)(q0 + wrow + mt * 16 + l15) * 256 +
                                    kc * 32 + q4 * 8);

  // ---- prologue: stage tile 0 into buffer 0 ----
  STAGE_KV(sp * SPLEN, 0);

  f32x4 O[2][16];
#pragma unroll
  for (int mt = 0; mt < 2; ++mt)
#pragma unroll
    for (int ft = 0; ft < 16; ++ft) O[mt][ft] = (f32x4){0.f, 0.f, 0.f, 0.f};
  float lrow[8];
#pragma unroll
  for (int i = 0; i < 8; ++i) lrow[i] = 0.f;

  u16* swp = &pbuf[wave][0];

#pragma unroll 1
  for (int it = 0; it < ITERS; ++it) {
    const int cur = it & 1;
    const int key0 = sp * SPLEN + it * BN;

    // tile `it` landed (own loads) + all waves' loads landed (barrier)
    asm volatile("s_waitcnt vmcnt(0)" ::: "memory");
    __syncthreads();

    // prefetch tile it+1 into the other buffer; waits on it happen next iter
    if (it + 1 < ITERS) STAGE_KV(key0 + BN, cur ^ 1);

    // ---- S = Q K^T ----
    f32x4 S[2][2];
#pragma unroll
    for (int mt = 0; mt < 2; ++mt)
#pragma unroll
      for (int nt = 0; nt < 2; ++nt) S[mt][nt] = (f32x4){0.f, 0.f, 0.f, 0.f};

#pragma unroll
    for (int kc = 0; kc < 8; ++kc) {
#pragma unroll
      for (int nt = 0; nt < 2; ++nt) {
        bf16x8 kf = *(const bf16x8*)(&kbuf[cur][(nt * 16 + l15) * 256 +
                                     (((kc * 4 + q4) ^ (l15 & 7)) * 8)]);
#pragma unroll
        for (int mt = 0; mt < 2; ++mt)
          S[mt][nt] = mfma16(qa[mt][kc], kf, S[mt][nt]);
      }
    }

    // ---- decay + exp (fixed reference) ----
    f32x4 pk[2];
#pragma unroll
    for (int nt = 0; nt < 2; ++nt)
      pk[nt] = ((const f32x4*)pq)[key0 + nt * 16 + l15];

#pragma unroll
    for (int mt = 0; mt < 2; ++mt) {
#pragma unroll
      for (int r = 0; r < 4; ++r) {
        f32x4 pr = *(const f32x4*)pqs[wrow + mt * 16 + q4 * 4 + r];
        float lacc = 0.f;
#pragma unroll
        for (int nt = 0; nt < 2; ++nt) {
          float h = pr[3] + pk[nt][3];
          h = fmaf(-pr[0], pk[nt][0], h);
          h = fmaf(-pr[1], pk[nt][1], h);
          h = fmaf(-pr[2], pk[nt][2], h);
          h = fmaxf(h, 0.f);
          float dec = exp2_hw(fmaf(h, -LOG2E, DECC));  // (decay/16)*log2e
          float p = exp2_hw(S[mt][nt][r] * dec);
          S[mt][nt][r] = p;
          lacc += p;
        }
        lrow[mt * 4 + r] += lacc;
      }
    }

    // ---- P tile (bf16) into per-wave pbuf ----
    asm volatile("" ::: "memory");
#pragma unroll
    for (int mt = 0; mt < 2; ++mt)
#pragma unroll
      for (int nt = 0; nt < 2; ++nt) {
        uint32_t p01 = pk_bf(S[mt][nt][0], S[mt][nt][1]);
        uint32_t p23 = pk_bf(S[mt][nt][2], S[mt][nt][3]);
        const int rr = (mt * 16 + q4 * 4) * 40 + nt * 16 + l15;
        swp[rr]          = (u16)p01;
        swp[rr + 40]     = (u16)(p01 >> 16);
        swp[rr + 80]     = (u16)p23;
        swp[rr + 120]    = (u16)(p23 >> 16);
      }
    asm volatile("s_waitcnt lgkmcnt(0)" ::: "memory");  // P visible to own reads
    asm volatile("" ::: "memory");

    // ---- O += P V ----
    bf16x8 pa[2];
#pragma unroll
    for (int mt = 0; mt < 2; ++mt)
      pa[mt] = *(const bf16x8*)(&pbuf[wave][(mt * 16 + l15) * 40 + q4 * 8]);
#pragma unroll
    for (int ft = 0; ft < 16; ++ft) {
      bf16x8 vf = *(const bf16x8*)(&vbuf[cur][(ft * 16 + l15) * 32 +
                                   ((q4 ^ (l15 & 3)) * 8)]);
#pragma unroll
      for (int mt = 0; mt < 2; ++mt)
        O[mt][ft] = mfma16(pa[mt], vf, O[mt][ft]);
    }
  }

  // ---- epilogue: cross-lane row sums, write partial O and l ----
#pragma unroll
  for (int i = 0; i < 8; ++i) lrow[i] = rowsum16(lrow[i]);

#pragma unroll
  for (int mt = 0; mt < 2; ++mt)
#pragma unroll
    for (int ft = 0; ft < 16; ++ft)
#pragma unroll
      for (int r = 0; r < 4; ++r) {
        int row = q0 + wrow + mt * 16 + q4 * 4 + r;
        Op[((size_t)sp * NTOK + row) * 256 + ft * 16 + l15] = f2bf(O[mt][ft][r]);
      }
  if (l15 == 0) {
#pragma unroll
    for (int mt = 0; mt < 2; ++mt)
#pragma unroll
      for (int r = 0; r < 4; ++r) {
        int row = q0 + wrow + mt * 16 + q4 * 4 + r;
        ml[sp * NTOK + row] = lrow[mt * 4 + r];
      }
  }
#undef STAGE_KV
}

// ---------------------------------------------------------------------------
// Kernel 3: combine splits: H = (sum O_s) / (1 + sum l_s) + residual.
// ---------------------------------------------------------------------------
__global__ __launch_bounds__(256) void combine_kernel(
    const float* __restrict__ X, const u16* __restrict__ Op,
    const float* __restrict__ ml, float* __restrict__ out) {
  const int row = blockIdx.x;
  const int f = threadIdx.x;
  float den = 1.f, num = 0.f;
#pragma unroll
  for (int s = 0; s < KSPLIT; ++s) {
    den += ml[s * NTOK + row];
    num += bf2f(Op[((size_t)s * NTOK + row) * 256 + f]);
  }
  out[(size_t)row * 256 + f] = num / den + X[(size_t)row * XSTRIDE + f];
}

// ---------------------------------------------------------------------------
extern "C" void kernel_launch(void* const* d_in, const int* in_sizes, int n_in,
                              void* d_out, int out_size, void* d_ws, size_t ws_size,
                              hipStream_t stream) {
  (void)in_sizes; (void)n_in; (void)out_size; (void)ws_size;
  const float* X  = (const float*)d_in[0];
  const float* WQ = (const float*)d_in[1];
  const float* bQ = (const float*)d_in[2];
  const float* WK = (const float*)d_in[3];
  const float* bK = (const float*)d_in[4];
  const float* WV = (const float*)d_in[5];
  const float* bV = (const float*)d_in[6];
  float* out = (float*)d_out;
  char* ws = (char*)d_ws;

  // workspace: Qb 4M | Kb 4M | Vt 4M | pq 128K | Op 16M | ml 128K
  u16*   Qb = (u16*)(ws);
  u16*   Kb = (u16*)(ws + (size_t)4 * 1024 * 1024);
  u16*   Vt = (u16*)(ws + (size_t)8 * 1024 * 1024);
  float* pq = (float*)(ws + (size_t)12 * 1024 * 1024);
  u16*   Op = (u16*)(ws + (size_t)12 * 1024 * 1024 + 131072);
  float* ml = (float*)(ws + (size_t)12 * 1024 * 1024 + 131072 +
                       (size_t)KSPLIT * NTOK * 256 * 2);

  pq_kernel<<<dim3(NTOK / 256), dim3(256), 0, stream>>>(X, pq);
  qkv_kernel<<<dim3(64, 12), dim3(256), 0, stream>>>(X, WQ, bQ, WK, bK, WV, bV,
                                                     Qb, Kb, Vt);
  attn_kernel<<<dim3(64, KSPLIT), dim3(256), 0, stream>>>(Qb, Kb, Vt, pq, Op, ml);
  combine_kernel<<<dim3(NTOK), dim3(256), 0, stream>>>(X, Op, ml, out);
}

// Round 7
// 235.861 us; speedup vs baseline: 2.2952x; 1.0725x over previous
//
#include <hip/hip_runtime.h>
#include <hip/hip_bf16.h>
#include <stdint.h>

#define NTOK 8192
#define XSTRIDE 259
#define LOG2E 1.4426950408889634f
#define DECC (-3.4712336270551023f)   /* -4 + log2(log2 e) */
#define KSPLIT 4
#define SPLEN (NTOK / KSPLIT)   /* 2048 */
#define BN 32
#define ITERS (SPLEN / BN)      /* 64 */

typedef __bf16 bf16x8 __attribute__((ext_vector_type(8)));
typedef float f32x4 __attribute__((ext_vector_type(4)));
typedef unsigned short u16;

union BF8 { u16 u[8]; bf16x8 v; };
union PB  { uint64_t d[2]; bf16x8 v; };

__device__ __forceinline__ u16 f2bf(float f) {
  uint32_t u = __float_as_uint(f);
  u += 0x7FFFu + ((u >> 16) & 1u);
  return (u16)(u >> 16);
}
__device__ __forceinline__ float bf2f(u16 h) {
  return __uint_as_float(((uint32_t)h) << 16);
}
__device__ __forceinline__ float exp2_hw(float x) {
  float r; asm("v_exp_f32 %0, %1" : "=v"(r) : "v"(x)); return r;
}
template<int CTRL>
__device__ __forceinline__ float dpp_rot(float x) {
  int i = __float_as_int(x);
  int y = __builtin_amdgcn_update_dpp(i, i, CTRL, 0xF, 0xF, false);
  return __int_as_float(y);
}
__device__ __forceinline__ float rowsum16(float x) {
  x += dpp_rot<0x121>(x);
  x += dpp_rot<0x122>(x);
  x += dpp_rot<0x124>(x);
  x += dpp_rot<0x128>(x);
  return x;
}
__device__ __forceinline__ f32x4 mfma16(bf16x8 a, bf16x8 b, f32x4 c) {
  return __builtin_amdgcn_mfma_f32_16x16x32_bf16(a, b, c, 0, 0, 0);
}
__device__ __forceinline__ void async16(const void* g, void* l) {
  __builtin_amdgcn_global_load_lds(
      (const __attribute__((address_space(1))) uint32_t*)g,
      (__attribute__((address_space(3))) uint32_t*)l, 16, 0, 0);
}

// ---------------------------------------------------------------------------
// Kernel 0: pq[row] = (px, py, pz, 0.5*|P|^2)
// ---------------------------------------------------------------------------
__global__ void pq_kernel(const float* __restrict__ X, float* __restrict__ pq) {
  int r = blockIdx.x * 256 + threadIdx.x;
  const float* xp = X + (size_t)r * XSTRIDE + 256;
  float x = xp[0], y = xp[1], z = xp[2];
  f32x4 o = { x, y, z, 0.5f * (x * x + y * y + z * z) };
  ((f32x4*)pq)[r] = o;
}

// ---------------------------------------------------------------------------
// Kernel 0b: W^T bf16 prep. Wt[o_global][k] = bf16(W[k][o]), o_global = which*256+o.
// ---------------------------------------------------------------------------
__global__ __launch_bounds__(256) void wprep_kernel(
    const float* __restrict__ WQ, const float* __restrict__ WK,
    const float* __restrict__ WV, u16* __restrict__ Wt) {
  const int o = blockIdx.x;          // 0..767
  const int which = o >> 8, oo = o & 255;
  const float* W = (which == 0) ? WQ : ((which == 1) ? WK : WV);
  const int k = threadIdx.x;
  Wt[(size_t)o * 256 + k] = f2bf(W[(size_t)k * 256 + oo]);
}

// ---------------------------------------------------------------------------
// Kernel 1: QKV projection.  grid (64 rowblocks, 12 col-chunks).
// wt staged from pre-transposed Wt via async16 (xor-swizzled, kbuf pattern).
// ---------------------------------------------------------------------------
__global__ __launch_bounds__(256) void qkv_kernel(
    const float* __restrict__ X, const u16* __restrict__ Wt,
    const float* __restrict__ bQ, const float* __restrict__ bK,
    const float* __restrict__ bV,
    u16* __restrict__ Qb, u16* __restrict__ Kb, u16* __restrict__ Vt) {
  __shared__ u16 wt[64 * 256];
  const int tid = threadIdx.x;
  const int lane = tid & 63;
  const int wave = tid >> 6;
  const int l15 = lane & 15;
  const int q4 = lane >> 4;
  const int rb = blockIdx.x;
  const int ch = blockIdx.y;
  const int which = ch >> 2;
  const int c0 = (ch & 3) * 64;
  const float* bias = (which == 0) ? bQ : ((which == 1) ? bK : bV);

  // X fragments first (older in vmcnt queue than staging)
  bf16x8 xa[2][8];
#pragma unroll
  for (int mt = 0; mt < 2; ++mt) {
    const int row = rb * 128 + wave * 32 + mt * 16 + l15;
#pragma unroll
    for (int kc = 0; kc < 8; ++kc) {
      const float* xp = X + (size_t)row * XSTRIDE + kc * 32 + q4 * 8;
      BF8 u;
#pragma unroll
      for (int jj = 0; jj < 8; ++jj) u.u[jj] = f2bf(xp[jj]);
      xa[mt][kc] = u.v;
    }
  }
  // stage wt (64 rows x 256) via async16, rows 512 B, xor swizzle r&7
  {
    const u16* Wsrc = Wt + (size_t)(which * 256 + c0) * 256;
    const int rb0 = wave * 16;
#pragma unroll
    for (int i = 0; i < 8; ++i) {
      int r = rb0 + i * 2 + (lane >> 5);
      int c = (lane & 31) ^ (r & 7);
      async16(Wsrc + (size_t)r * 256 + c * 8, wt + (rb0 + i * 2) * 256);
    }
  }
  asm volatile("s_waitcnt vmcnt(0)" ::: "memory");
  __syncthreads();

  f32x4 acc[2][4];
#pragma unroll
  for (int mt = 0; mt < 2; ++mt)
#pragma unroll
    for (int nt = 0; nt < 4; ++nt) acc[mt][nt] = (f32x4){0.f, 0.f, 0.f, 0.f};

#pragma unroll
  for (int kc = 0; kc < 8; ++kc) {
#pragma unroll
    for (int nt = 0; nt < 4; ++nt) {
      bf16x8 wf = *(const bf16x8*)(wt + (nt * 16 + l15) * 256 +
                                   (((kc * 4 + q4) ^ (l15 & 7)) * 8));
#pragma unroll
      for (int mt = 0; mt < 2; ++mt)
        acc[mt][nt] = mfma16(xa[mt][kc], wf, acc[mt][nt]);
    }
  }
  float bc[4];
#pragma unroll
  for (int nt = 0; nt < 4; ++nt) bc[nt] = bias[c0 + nt * 16 + l15];

#pragma unroll
  for (int mt = 0; mt < 2; ++mt)
#pragma unroll
    for (int nt = 0; nt < 4; ++nt)
#pragma unroll
      for (int r = 0; r < 4; ++r) {
        float v = acc[mt][nt][r] + bc[nt];
        int grow = rb * 128 + wave * 32 + mt * 16 + q4 * 4 + r;
        int gc = c0 + nt * 16 + l15;
        if (which == 2)      Vt[(size_t)gc * NTOK + grow] = f2bf(v);
        else if (which == 1) Kb[(size_t)grow * 256 + gc] = f2bf(v);
        else                 Qb[(size_t)grow * 256 + gc] = f2bf(v);
      }
}

// ---------------------------------------------------------------------------
// Kernel 2: flash attention, fully pipelined.
//  - ZERO vmem in loop except prefetch (pq keys staged to LDS with the tile;
//    in-order vmcnt no longer drained mid-iteration).
//  - PV runs one iteration behind: independent of softmax(t) -> overlap.
//  - K dbuf, V tribuf, P/pqk dbuf; ONE barrier per iter (its implicit
//    vmcnt(0) drain IS the prefetch wait, a full iteration after issue).
//  - pbuf stride 36 u16: writes ~2-way, reads via 2x b64 (8B-aligned).
// ---------------------------------------------------------------------------
__global__ __launch_bounds__(256, 1) void attn_kernel(
    const u16* __restrict__ Qb, const u16* __restrict__ Kb,
    const u16* __restrict__ Vt, const float* __restrict__ pq,
    u16* __restrict__ Op, float* __restrict__ ml) {
  __shared__ u16 kbuf[2][BN * 256];     // 16 KB x2
  __shared__ u16 vbuf[3][256 * BN];     // 16 KB x3
  __shared__ u16 pbuf[4][2][32 * 36];   // per-wave P, dbuf
  __shared__ float pqk[2][BN * 4];      // key-side pq, dbuf
  __shared__ float pqs[128][4];         // query-side pq

  const int tid = threadIdx.x;
  const int lane = tid & 63;
  const int wave = tid >> 6;
  const int l15 = lane & 15;
  const int q4 = lane >> 4;
  const int rb = blockIdx.x;
  const int sp = blockIdx.y;
  const int q0 = rb * 128;
  const int wrow = wave * 32;

  if (tid < 128) ((f32x4*)pqs)[tid] = ((const f32x4*)pq)[q0 + tid];

#define STAGE(T)                                                              \
  do {                                                                        \
    const int key0_ = sp * SPLEN + (T) * BN;                                  \
    const int kb_ = (T) & 1, vb_ = (T) % 3, pb_ = (T) & 1;                    \
    if (wave < 2) {                                                           \
      const int rb0 = wave * 16;                                              \
      _Pragma("unroll")                                                       \
      for (int i = 0; i < 8; ++i) {                                           \
        int r = rb0 + i * 2 + (lane >> 5);                                    \
        int c = (lane & 31) ^ (r & 7);                                        \
        async16(Kb + (size_t)(key0_ + r) * 256 + c * 8,                       \
                &kbuf[kb_][(rb0 + i * 2) * 256]);                             \
      }                                                                       \
    } else {                                                                  \
      const int fb0 = (wave - 2) * 128;                                       \
      _Pragma("unroll")                                                       \
      for (int i = 0; i < 8; ++i) {                                           \
        int f = fb0 + i * 16 + (lane >> 2);                                   \
        int c = (lane & 3) ^ (f & 3);                                         \
        async16(Vt + (size_t)f * NTOK + key0_ + c * 8,                        \
                &vbuf[vb_][(fb0 + i * 16) * 32]);                             \
      }                                                                       \
      if (wave == 3 && lane < 32)                                             \
        async16(((const f32x4*)pq) + key0_ + lane, &pqk[pb_][0]);             \
    }                                                                         \
  } while (0)

  // softmax for tile T: consumes S (QK result), produces P in pbuf slot T&1
#define SOFTMAX_P(T)                                                          \
  do {                                                                        \
    const int pb_ = (T) & 1;                                                  \
    f32x4 pk[2];                                                              \
    _Pragma("unroll")                                                         \
    for (int nt = 0; nt < 2; ++nt)                                            \
      pk[nt] = ((const f32x4*)pqk[pb_])[nt * 16 + l15];                       \
    _Pragma("unroll")                                                         \
    for (int mt = 0; mt < 2; ++mt) {                                          \
      _Pragma("unroll")                                                       \
      for (int r = 0; r < 4; ++r) {                                           \
        f32x4 pr = *(const f32x4*)pqs[wrow + mt * 16 + q4 * 4 + r];           \
        float lacc = 0.f;                                                     \
        _Pragma("unroll")                                                     \
        for (int nt = 0; nt < 2; ++nt) {                                      \
          float h = pr[3] + pk[nt][3];                                        \
          h = fmaf(-pr[0], pk[nt][0], h);                                     \
          h = fmaf(-pr[1], pk[nt][1], h);                                     \
          h = fmaf(-pr[2], pk[nt][2], h);                                     \
          h = fmaxf(h, 0.f);                                                  \
          float dec = exp2_hw(fmaf(h, -LOG2E, DECC));                         \
          float p = exp2_hw(S[mt][nt][r] * dec);                              \
          S[mt][nt][r] = p;                                                   \
          lacc += p;                                                          \
        }                                                                     \
        lrow[mt * 4 + r] += lacc;                                             \
      }                                                                       \
    }                                                                         \
    asm volatile("" ::: "memory");                                            \
    _Pragma("unroll")                                                         \
    for (int mt = 0; mt < 2; ++mt)                                            \
      _Pragma("unroll")                                                       \
      for (int nt = 0; nt < 2; ++nt)                                          \
        _Pragma("unroll")                                                     \
        for (int r = 0; r < 4; ++r)                                           \
          pbuf[wave][pb_][(mt * 16 + q4 * 4 + r) * 36 + nt * 16 + l15] =      \
              f2bf(S[mt][nt][r]);                                             \
    asm volatile("" ::: "memory");                                            \
  } while (0)

#define QK(T)                                                                 \
  do {                                                                        \
    const int kb_ = (T) & 1;                                                  \
    _Pragma("unroll")                                                         \
    for (int mt = 0; mt < 2; ++mt)                                            \
      _Pragma("unroll")                                                       \
      for (int nt = 0; nt < 2; ++nt) S[mt][nt] = (f32x4){0.f, 0.f, 0.f, 0.f};\
    _Pragma("unroll")                                                         \
    for (int kc = 0; kc < 8; ++kc) {                                          \
      _Pragma("unroll")                                                       \
      for (int nt = 0; nt < 2; ++nt) {                                        \
        bf16x8 kf = *(const bf16x8*)(&kbuf[kb_][(nt * 16 + l15) * 256 +       \
                                     (((kc * 4 + q4) ^ (l15 & 7)) * 8)]);     \
        _Pragma("unroll")                                                     \
        for (int mt = 0; mt < 2; ++mt)                                        \
          S[mt][nt] = mfma16(qa[mt][kc], kf, S[mt][nt]);                      \
      }                                                                       \
    }                                                                         \
  } while (0)

#define PV(T)                                                                 \
  do {                                                                        \
    const int pb_ = (T) & 1, vb_ = (T) % 3;                                   \
    bf16x8 pa[2];                                                             \
    _Pragma("unroll")                                                         \
    for (int mt = 0; mt < 2; ++mt) {                                          \
      PB pb;                                                                  \
      const u16* pp = &pbuf[wave][pb_][(mt * 16 + l15) * 36 + q4 * 8];        \
      pb.d[0] = *(const uint64_t*)(pp);                                       \
      pb.d[1] = *(const uint64_t*)(pp + 4);                                   \
      pa[mt] = pb.v;                                                          \
    }                                                                         \
    _Pragma("unroll")                                                         \
    for (int ft = 0; ft < 16; ++ft) {                                         \
      bf16x8 vf = *(const bf16x8*)(&vbuf[vb_][(ft * 16 + l15) * 32 +          \
                                   ((q4 ^ (l15 & 3)) * 8)]);                  \
      _Pragma("unroll")                                                       \
      for (int mt = 0; mt < 2; ++mt)                                          \
        O[mt][ft] = mfma16(pa[mt], vf, O[mt][ft]);                            \
    }                                                                         \
  } while (0)

  // Q fragments: persistent in registers
  bf16x8 qa[2][8];
#pragma unroll
  for (int mt = 0; mt < 2; ++mt)
#pragma unroll
    for (int kc = 0; kc < 8; ++kc)
      qa[mt][kc] = *(const bf16x8*)(Qb + (size_t)(q0 + wrow + mt * 16 + l15) * 256 +
                                    kc * 32 + q4 * 8);

  f32x4 O[2][16];
#pragma unroll
  for (int mt = 0; mt < 2; ++mt)
#pragma unroll
    for (int ft = 0; ft < 16; ++ft) O[mt][ft] = (f32x4){0.f, 0.f, 0.f, 0.f};
  float lrow[8];
#pragma unroll
  for (int i = 0; i < 8; ++i) lrow[i] = 0.f;

  f32x4 S[2][2];

  // prologue: tile 0 staged; iter 0 peeled (no PV yet)
  STAGE(0);
  asm volatile("s_waitcnt vmcnt(0)" ::: "memory");
  __syncthreads();
  STAGE(1);
  QK(0);
  SOFTMAX_P(0);

#pragma unroll 1
  for (int it = 1; it < ITERS; ++it) {
    asm volatile("s_waitcnt vmcnt(0)" ::: "memory");
    __syncthreads();
    const int nx = (it + 1 < ITERS) ? (it + 1) : it;  // clamp: rewrite of
    STAGE(nx);  // identical bytes on last iter — benign race by construction
    QK(it);
    PV(it - 1);
    SOFTMAX_P(it);
  }
  asm volatile("" ::: "memory");
  PV(ITERS - 1);

  // epilogue
#pragma unroll
  for (int i = 0; i < 8; ++i) lrow[i] = rowsum16(lrow[i]);

#pragma unroll
  for (int mt = 0; mt < 2; ++mt)
#pragma unroll
    for (int ft = 0; ft < 16; ++ft)
#pragma unroll
      for (int r = 0; r < 4; ++r) {
        int row = q0 + wrow + mt * 16 + q4 * 4 + r;
        Op[((size_t)sp * NTOK + row) * 256 + ft * 16 + l15] = f2bf(O[mt][ft][r]);
      }
  if (l15 == 0) {
#pragma unroll
    for (int mt = 0; mt < 2; ++mt)
#pragma unroll
      for (int r = 0; r < 4; ++r) {
        int row = q0 + wrow + mt * 16 + q4 * 4 + r;
        ml[sp * NTOK + row] = lrow[mt * 4 + r];
      }
  }
#undef STAGE
#undef SOFTMAX_P
#undef QK
#undef PV
}

// ---------------------------------------------------------------------------
// Kernel 3: combine splits: H = (sum O_s) / (1 + sum l_s) + residual.
// ---------------------------------------------------------------------------
__global__ __launch_bounds__(256) void combine_kernel(
    const float* __restrict__ X, const u16* __restrict__ Op,
    const float* __restrict__ ml, float* __restrict__ out) {
  const int row = blockIdx.x;
  const int f = threadIdx.x;
  float den = 1.f, num = 0.f;
#pragma unroll
  for (int s = 0; s < KSPLIT; ++s) {
    den += ml[s * NTOK + row];
    num += bf2f(Op[((size_t)s * NTOK + row) * 256 + f]);
  }
  out[(size_t)row * 256 + f] = num / den + X[(size_t)row * XSTRIDE + f];
}

// ---------------------------------------------------------------------------
extern "C" void kernel_launch(void* const* d_in, const int* in_sizes, int n_in,
                              void* d_out, int out_size, void* d_ws, size_t ws_size,
                              hipStream_t stream) {
  (void)in_sizes; (void)n_in; (void)out_size; (void)ws_size;
  const float* X  = (const float*)d_in[0];
  const float* WQ = (const float*)d_in[1];
  const float* bQ = (const float*)d_in[2];
  const float* WK = (const float*)d_in[3];
  const float* bK = (const float*)d_in[4];
  const float* WV = (const float*)d_in[5];
  const float* bV = (const float*)d_in[6];
  float* out = (float*)d_out;
  char* ws = (char*)d_ws;

  // ws: Qb 4M | Kb 4M | Vt 4M | pq 128K | Wt 384K | Op 16M | ml 128K
  u16*   Qb = (u16*)(ws);
  u16*   Kb = (u16*)(ws + ((size_t)4 << 20));
  u16*   Vt = (u16*)(ws + ((size_t)8 << 20));
  float* pq = (float*)(ws + ((size_t)12 << 20));
  u16*   Wt = (u16*)(ws + ((size_t)12 << 20) + 131072);
  u16*   Op = (u16*)(ws + ((size_t)12 << 20) + 131072 + 393216);
  float* ml = (float*)(ws + ((size_t)12 << 20) + 131072 + 393216 +
                       (size_t)KSPLIT * NTOK * 256 * 2);

  pq_kernel<<<dim3(NTOK / 256), dim3(256), 0, stream>>>(X, pq);
  wprep_kernel<<<dim3(768), dim3(256), 0, stream>>>(WQ, WK, WV, Wt);
  qkv_kernel<<<dim3(64, 12), dim3(256), 0, stream>>>(X, Wt, bQ, bK, bV,
                                                     Qb, Kb, Vt);
  attn_kernel<<<dim3(64, KSPLIT), dim3(256), 0, stream>>>(Qb, Kb, Vt, pq, Op, ml);
  combine_kernel<<<dim3(NTOK), dim3(256), 0, stream>>>(X, Op, ml, out);
}